// Round 7
// baseline (373.328 us; speedup 1.0000x reference)
//
#include <hip/hip_runtime.h>
#include <math.h>

#define BATCH 4096
#define SEQ_T 512
#define ISZ   4
#define HID   64
#define OSZ   40
#define RPB   16     // batch cols per wave; grid = 256 blocks x 1 wave = 1/CU

typedef __attribute__((ext_vector_type(8))) _Float16     half8;
typedef __attribute__((ext_vector_type(2))) _Float16     half2v;
typedef __attribute__((ext_vector_type(4))) float        float4v;
typedef __attribute__((ext_vector_type(4))) unsigned int uint4v;

static __device__ __forceinline__ unsigned int pk_u32(float a, float b) {
    return __builtin_bit_cast(unsigned int, __builtin_amdgcn_cvt_pkrtz(a, b));
}

// tanh(z) from pre-scaled s = 2*log2e*z (scale folded into the weights):
// tanh = 1 - 2*rcp(exp2(s)+1). Saturating, NaN-free, same numerics as r6.
static __device__ __forceinline__ float4v tanh4(float4v s) {
    float4v r;
    #pragma unroll
    for (int i = 0; i < 4; ++i) {
        float e = __builtin_amdgcn_exp2f(s[i]);
        r[i] = fmaf(-2.0f, __builtin_amdgcn_rcpf(e + 1.0f), 1.0f);
    }
    return r;
}

// ---- sigma-permuted single-wave RNN (r6 post-mortem) ----
// The 4-wave M-split pays ~300cy/update of LDS write->drain->barrier->read to
// exchange h across SIMDs (~40% of the 715cy chain). Instead, ONE wave computes
// all 4 M-tiles with A-rows permuted by
//   rho_m(i) = 32*(m>>1) + 8*(i>>2) + 4*(m&1) + (i&3)
// so lane(n,q)'s D value (tile m, elem r) IS true h-row 32(m>>1)+8q+4(m&1)+r =
// exactly B-slot k it needs next step (D: row=4q+r,col=n; B: k=8q+j,col=n).
// D->B becomes in-register pk_f16 packing: no LDS, no barriers, no shuffles.
// xp is folded into MFMA as a 3rd K-chunk [Wih_hi|Wih_hi|Wih_lo|bias split]
// against B_x=[x_hi|x_lo|1], with ALL weights pre-scaled by 2*log2e so the
// MFMA output feeds exp2 directly. Wall = wave issue (~600cy/update), chain
// latency (~220, LDS-free) hides under it.
__global__ __launch_bounds__(64, 1)
void rnn_sigma_kernel(const float* __restrict__ x,
                      const float* __restrict__ W_ih,
                      const float* __restrict__ W_hh,
                      const float* __restrict__ b_ih,
                      const float* __restrict__ b_hh,
                      const float* __restrict__ fc_W,
                      const float* __restrict__ fc_b,
                      float* __restrict__ out)
{
    __shared__ float hf[RPB][HID + 4];   // epilogue only

    const int lane = threadIdx.x;        // 0..63
    const int n    = lane & 15;          // batch col (B/D col, A row)
    const int q    = lane >> 4;
    const int blk0 = blockIdx.x * RPB;
    const float SC = 2.885390081777927f; // 2*log2(e)
    const bool qodd = (q & 1) != 0;

    // ---- A fragments: rho_m-permuted rows, scaled by SC, 2-term f16 split ----
    half8 Ahi[4][2], Alo[4][2], Ax[4];
    #pragma unroll
    for (int m = 0; m < 4; ++m) {
        const int rho = 32 * (m >> 1) + 8 * (n >> 2) + 4 * (m & 1) + (n & 3);
        const float* wr = W_hh + rho * HID + 8 * q;
        #pragma unroll
        for (int ck = 0; ck < 2; ++ck) {
            #pragma unroll
            for (int j = 0; j < 8; ++j) {
                float w = SC * wr[32 * ck + j];
                _Float16 wh = (_Float16)w;
                Ahi[m][ck][j] = wh;
                Alo[m][ck][j] = (_Float16)(w - (float)wh);
            }
        }
        // A_x: k=8q+j. q0: Wih_hi[0..3], bias_hi at j=4. q1: Wih_hi (pairs with
        // x_lo), bias_lo at j=4. q2: Wih_lo (pairs with x_hi). q3: zero.
        half8 a;
        #pragma unroll
        for (int j = 0; j < 8; ++j) a[j] = (_Float16)0.f;
        #pragma unroll
        for (int i = 0; i < ISZ; ++i) {
            float w = SC * W_ih[rho * ISZ + i];
            _Float16 wh = (_Float16)w;
            _Float16 wl = (_Float16)(w - (float)wh);
            a[i] = (q == 2) ? wl : ((q <= 1) ? wh : (_Float16)0.f);
        }
        {
            float bias = SC * (b_ih[rho] + b_hh[rho]);
            _Float16 bh = (_Float16)bias;
            _Float16 bl = (_Float16)(bias - (float)bh);
            a[4] = (q == 0) ? bh : ((q == 1) ? bl : (_Float16)0.f);
        }
        Ax[m] = a;
    }

    // ---- x pipeline: 4 named regs, reload-in-place (r6 pattern), stride 1 ----
    const float* xrow = x + (size_t)(blk0 + n) * SEQ_T * ISZ;
    float4v xa = *(const float4v*)(xrow + 0 * ISZ);
    float4v xb = *(const float4v*)(xrow + 1 * ISZ);
    float4v xc = *(const float4v*)(xrow + 2 * ISZ);
    float4v xd = *(const float4v*)(xrow + 3 * ISZ);
    int tnext = 4;

    // ---- h state in B-fragment form: hi/lo per K-chunk; h(0)=0 ----
    half8 Bhi0, Bhi1, Blo0, Blo1;
    {
        uint4v z = {0u, 0u, 0u, 0u};
        Bhi0 = Bhi1 = Blo0 = Blo1 = __builtin_bit_cast(half8, z);
    }
    float4v tq0 = {0,0,0,0}, tq1 = {0,0,0,0}, tq2 = {0,0,0,0}, tq3 = {0,0,0,0};

#define MFMA16(A, B, C) __builtin_amdgcn_mfma_f32_16x16x32_f16((A), (B), (C), 0, 0, 0)

#define XRELOAD(XR)                                                            \
    { int tn = (tnext < SEQ_T) ? tnext : (SEQ_T - 1);                          \
      XR = *(const float4v*)(xrow + (size_t)tn * ISZ); ++tnext; }

#define STEP(XR)                                                               \
    {                                                                          \
        /* B_x: [x_hi | x_lo | 1] selected by q (A_x is 0 wherever unused) */  \
        unsigned int xh01 = pk_u32(XR[0], XR[1]);                              \
        unsigned int xh23 = pk_u32(XR[2], XR[3]);                              \
        half2v ph01 = __builtin_bit_cast(half2v, xh01);                        \
        half2v ph23 = __builtin_bit_cast(half2v, xh23);                        \
        unsigned int xl01 = pk_u32(XR[0] - (float)ph01[0],                     \
                                   XR[1] - (float)ph01[1]);                    \
        unsigned int xl23 = pk_u32(XR[2] - (float)ph23[0],                     \
                                   XR[3] - (float)ph23[1]);                    \
        uint4v bxw = { qodd ? xl01 : xh01, qodd ? xl23 : xh23,                 \
                       0x00003C00u, 0u };                                      \
        half8 Bx = __builtin_bit_cast(half8, bxw);                             \
        const float4v zz = {0.f, 0.f, 0.f, 0.f};                               \
        /* per m-tile: 7 C-chained MFMAs (xp + 2ck x {hihi, hilo, lohi}) */    \
        float4v a0 = MFMA16(Ax[0], Bx, zz);                                    \
        float4v a1 = MFMA16(Ax[1], Bx, zz);                                    \
        float4v a2 = MFMA16(Ax[2], Bx, zz);                                    \
        float4v a3 = MFMA16(Ax[3], Bx, zz);                                    \
        a0 = MFMA16(Ahi[0][0], Bhi0, a0); a1 = MFMA16(Ahi[1][0], Bhi0, a1);    \
        a2 = MFMA16(Ahi[2][0], Bhi0, a2); a3 = MFMA16(Ahi[3][0], Bhi0, a3);    \
        a0 = MFMA16(Ahi[0][1], Bhi1, a0); a1 = MFMA16(Ahi[1][1], Bhi1, a1);    \
        a2 = MFMA16(Ahi[2][1], Bhi1, a2); a3 = MFMA16(Ahi[3][1], Bhi1, a3);    \
        a0 = MFMA16(Ahi[0][0], Blo0, a0); a1 = MFMA16(Ahi[1][0], Blo0, a1);    \
        a2 = MFMA16(Ahi[2][0], Blo0, a2); a3 = MFMA16(Ahi[3][0], Blo0, a3);    \
        a0 = MFMA16(Ahi[0][1], Blo1, a0); a1 = MFMA16(Ahi[1][1], Blo1, a1);    \
        a2 = MFMA16(Ahi[2][1], Blo1, a2); a3 = MFMA16(Ahi[3][1], Blo1, a3);    \
        a0 = MFMA16(Alo[0][0], Bhi0, a0); a1 = MFMA16(Alo[1][0], Bhi0, a1);    \
        a2 = MFMA16(Alo[2][0], Bhi0, a2); a3 = MFMA16(Alo[3][0], Bhi0, a3);    \
        a0 = MFMA16(Alo[0][1], Bhi1, a0); a1 = MFMA16(Alo[1][1], Bhi1, a1);    \
        a2 = MFMA16(Alo[2][1], Bhi1, a2); a3 = MFMA16(Alo[3][1], Bhi1, a3);    \
        tq0 = tanh4(a0); tq1 = tanh4(a1); tq2 = tanh4(a2); tq3 = tanh4(a3);    \
        /* D -> B: pk hi, then lo = h - hi, pk lo; words land in slot order */ \
        unsigned int h001 = pk_u32(tq0[0], tq0[1]), h023 = pk_u32(tq0[2], tq0[3]); \
        unsigned int h101 = pk_u32(tq1[0], tq1[1]), h123 = pk_u32(tq1[2], tq1[3]); \
        unsigned int h201 = pk_u32(tq2[0], tq2[1]), h223 = pk_u32(tq2[2], tq2[3]); \
        unsigned int h301 = pk_u32(tq3[0], tq3[1]), h323 = pk_u32(tq3[2], tq3[3]); \
        half2v p001 = __builtin_bit_cast(half2v, h001), p023 = __builtin_bit_cast(half2v, h023); \
        half2v p101 = __builtin_bit_cast(half2v, h101), p123 = __builtin_bit_cast(half2v, h123); \
        half2v p201 = __builtin_bit_cast(half2v, h201), p223 = __builtin_bit_cast(half2v, h223); \
        half2v p301 = __builtin_bit_cast(half2v, h301), p323 = __builtin_bit_cast(half2v, h323); \
        unsigned int l001 = pk_u32(tq0[0] - (float)p001[0], tq0[1] - (float)p001[1]); \
        unsigned int l023 = pk_u32(tq0[2] - (float)p023[0], tq0[3] - (float)p023[1]); \
        unsigned int l101 = pk_u32(tq1[0] - (float)p101[0], tq1[1] - (float)p101[1]); \
        unsigned int l123 = pk_u32(tq1[2] - (float)p123[0], tq1[3] - (float)p123[1]); \
        unsigned int l201 = pk_u32(tq2[0] - (float)p201[0], tq2[1] - (float)p201[1]); \
        unsigned int l223 = pk_u32(tq2[2] - (float)p223[0], tq2[3] - (float)p223[1]); \
        unsigned int l301 = pk_u32(tq3[0] - (float)p301[0], tq3[1] - (float)p301[1]); \
        unsigned int l323 = pk_u32(tq3[2] - (float)p323[0], tq3[3] - (float)p323[1]); \
        uint4v bh0 = {h001, h023, h101, h123};                                 \
        uint4v bh1 = {h201, h223, h301, h323};                                 \
        uint4v bl0 = {l001, l023, l101, l123};                                 \
        uint4v bl1 = {l201, l223, l301, l323};                                 \
        Bhi0 = __builtin_bit_cast(half8, bh0);                                 \
        Bhi1 = __builtin_bit_cast(half8, bh1);                                 \
        Blo0 = __builtin_bit_cast(half8, bl0);                                 \
        Blo1 = __builtin_bit_cast(half8, bl1);                                 \
    }

    for (int t = 0; t < SEQ_T; t += 4) {
        STEP(xa) XRELOAD(xa)
        STEP(xb) XRELOAD(xb)
        STEP(xc) XRELOAD(xc)
        STEP(xd) XRELOAD(xd)
    }
#undef STEP
#undef XRELOAD
#undef MFMA16

    // ---- fc epilogue: lane(n,q) tile m elem r holds true h-row
    //      32(m>>1)+8q+4(m&1)+r of batch col n ----
    #pragma unroll
    for (int m = 0; m < 4; ++m) {
        const int row = 32 * (m >> 1) + 8 * q + 4 * (m & 1);
        float4v tv = (m == 0) ? tq0 : (m == 1) ? tq1 : (m == 2) ? tq2 : tq3;
        #pragma unroll
        for (int r = 0; r < 4; ++r) hf[n][row + r] = tv[r];
    }
    __syncthreads();
    for (int it = lane; it < RPB * OSZ; it += 64) {
        const int b = it / OSZ;
        const int o = it - b * OSZ;
        const float* wo = fc_W + o * HID;
        float acc = fc_b[o];
        #pragma unroll
        for (int j = 0; j < HID; ++j)
            acc = fmaf(hf[b][j], wo[j], acc);
        out[(size_t)(blk0 + b) * OSZ + o] = acc;
    }
}

extern "C" void kernel_launch(void* const* d_in, const int* in_sizes, int n_in,
                              void* d_out, int out_size, void* d_ws, size_t ws_size,
                              hipStream_t stream) {
    const float* x    = (const float*)d_in[0];
    const float* W_ih = (const float*)d_in[1];
    const float* W_hh = (const float*)d_in[2];
    const float* b_ih = (const float*)d_in[3];
    const float* b_hh = (const float*)d_in[4];
    const float* fc_W = (const float*)d_in[5];
    const float* fc_b = (const float*)d_in[6];
    float* out = (float*)d_out;

    rnn_sigma_kernel<<<BATCH / RPB, 64, 0, stream>>>(
        x, W_ih, W_hh, b_ih, b_hh, fc_W, fc_b, out);
}

// Round 8
// 190.256 us; speedup vs baseline: 1.9622x; 1.9622x over previous
//
#include <hip/hip_runtime.h>
#include <math.h>

#define BATCH 4096
#define SEQ_T 512
#define ISZ   4
#define HID   64
#define OSZ   40
#define RPB   16     // batch rows per block (MFMA N); grid = 256 = 1 block/CU

typedef __attribute__((ext_vector_type(8))) _Float16     half8;
typedef __attribute__((ext_vector_type(2))) _Float16     half2v;
typedef __attribute__((ext_vector_type(4))) float        float4v;
typedef __attribute__((ext_vector_type(2))) unsigned int uint2v;

static __device__ __forceinline__ half2v pk_f16(float a, float b) {
    return __builtin_bit_cast(half2v, __builtin_amdgcn_cvt_pkrtz(a, b)); // v_cvt_pkrtz_f16_f32
}

// tanh(x) = 1 - 2/(exp2(x*2*log2e)+1); saturating, NaN-free (r4/r6 form)
static __device__ __forceinline__ float fast_tanh(float x) {
    float e = __builtin_amdgcn_exp2f(x * 2.885390081777927f);
    return fmaf(-2.0f, __builtin_amdgcn_rcpf(e + 1.0f), 1.0f);
}

// LDS-only barrier: ds_writes drained (lgkmcnt), global x prefetches stay in flight.
#define LDS_BARRIER() asm volatile("s_waitcnt lgkmcnt(0)\n\ts_barrier" ::: "memory")

// r6 phase-split base (152us, best): grp0 even updates, grp1 odd; dependent
// chains tile the timeline; xp precomputed in the shadow phase; 4-deep named-reg
// x pipeline. r7 proved the 4-wave M-split's LDS handoff (~300cy) is cheaper
// than concentrating the tanh/pack tail on one SIMD (sigma kernel: 2x slower,
// bank-conflicts 0 but issue-bound on a single SIMD).
// r8 single change: h stored as PLAIN f16 (drop the h-lo residual term), W keeps
// the 2-term compensated split (static, the dominant accuracy term). Chain:
// MFMA 6->4 and depth 3->2, ds_reads 4->2, pack halved, ds_write 2->1.
__global__ __launch_bounds__(512, 1)
void rnn_f16x2_kernel(const float* __restrict__ x,
                      const float* __restrict__ W_ih,
                      const float* __restrict__ W_hh,
                      const float* __restrict__ b_ih,
                      const float* __restrict__ b_hh,
                      const float* __restrict__ fc_W,
                      const float* __restrict__ fc_b,
                      float* __restrict__ out)
{
    // hterm[buf][g][n][j] = h[k=8g+j] (f16 hi only) for batch col n.
    // Reader lane(n,q): b128 at [g=4c+q? -> (q) and (4+q)][n][0] -> banks (4n)%32,
    // 2-way alias (free). Writer lane(n,q) wave wg: g=2wg+(q>>1), j0=4(q&1):
    // one b64, 2-way (free).
    __shared__ __attribute__((aligned(16))) _Float16 hterm[2][8][16][8];
    __shared__ __attribute__((aligned(16))) float hf[16][68];

    const int tid  = threadIdx.x;
    const int grp  = tid >> 8;         // 0: even updates, 1: odd updates
    const int wg   = (tid >> 6) & 3;   // wave-in-group: M-slice of H
    const int lane = tid & 63;
    const int n    = lane & 15;        // A: row m; B/C/D: batch col n
    const int q    = lane >> 4;
    const int blk0 = blockIdx.x * RPB;

    // h(0) = 0: zero both buffers
    {
        unsigned int* p = (unsigned int*)hterm;
        #pragma unroll
        for (int i = tid; i < (int)(sizeof(hterm) / 4); i += 512) p[i] = 0u;
    }

    // ---- static A fragments: W_hh row 16wg+n, 2-term fp16 split, K-chunks c=0,1 ----
    half8 A10, A11, A20, A21;   // A1x = hi term, A2x = residual term
    {
        const float* wr = W_hh + (16 * wg + n) * HID;
        #pragma unroll
        for (int j = 0; j < 8; ++j) {
            float f0 = wr[     8 * q + j];
            float f1 = wr[32 + 8 * q + j];
            _Float16 h0 = (_Float16)f0; A10[j] = h0; A20[j] = (_Float16)(f0 - (float)h0);
            _Float16 h1 = (_Float16)f1; A11[j] = h1; A21[j] = (_Float16)(f1 - (float)h1);
        }
    }

    // ---- fp32 x-projection weights + bias for C rows 16wg + 4q + r ----
    const int r0 = 16 * wg + 4 * q;
    float wih[4][4], bias[4];
    #pragma unroll
    for (int r = 0; r < 4; ++r) {
        bias[r] = b_ih[r0 + r] + b_hh[r0 + r];
        #pragma unroll
        for (int i = 0; i < ISZ; ++i) wih[r][i] = W_ih[(r0 + r) * ISZ + i];
    }

    // ---- 4-deep named x pipeline: this group's updates are u = grp, grp+2, ... ----
    const float* xrow = x + (size_t)(blk0 + n) * SEQ_T * ISZ;
    float4v xa = *(const float4v*)(xrow + (size_t)(grp    ) * ISZ);
    float4v xb = *(const float4v*)(xrow + (size_t)(grp + 2) * ISZ);
    float4v xc = *(const float4v*)(xrow + (size_t)(grp + 4) * ISZ);
    float4v xd = *(const float4v*)(xrow + (size_t)(grp + 6) * ISZ);
    int tnext = grp + 8;

    const int gw = 2 * wg + (q >> 1);
    const int j0 = 4 * (q & 1);

    float p0, p1, p2, p3;
    float hl0 = 0.f, hl1 = 0.f, hl2 = 0.f, hl3 = 0.f;

    __syncthreads();   // zero-init visible (prologue: full drain fine)

#define MFMA16(A, B, C) __builtin_amdgcn_mfma_f32_16x16x32_f16((A), (B), (C), 0, 0, 0)

// Consume XR (xp projection), then reload the SAME register in place for use
// 4 phase-pairs later (r6 pattern: no moves touch an in-flight load).
#define XP_FROM(XR)                                                            \
    {                                                                          \
        p0 = bias[0]; p1 = bias[1]; p2 = bias[2]; p3 = bias[3];                \
        _Pragma("unroll")                                                      \
        for (int i = 0; i < ISZ; ++i) {                                        \
            p0 = fmaf(XR[i], wih[0][i], p0);                                   \
            p1 = fmaf(XR[i], wih[1][i], p1);                                   \
            p2 = fmaf(XR[i], wih[2][i], p2);                                   \
            p3 = fmaf(XR[i], wih[3][i], p3);                                   \
        }                                                                      \
    }

#define XRELOAD(XR)                                                            \
    {                                                                          \
        int tn = tnext; if (tn > SEQ_T - 1) tn = SEQ_T - 1;                    \
        XR = *(const float4v*)(xrow + (size_t)tn * ISZ);                       \
        tnext += 2;                                                            \
    }

// Two 2-deep C-chained accumulator chains: hi-W x h (chain A, xp as C) and
// lo-W x h (chain B). C-chaining issues near back-to-back (r5 lesson).
#define ACTIVE_STEP(RB, WB)                                                    \
    {                                                                          \
        half8 B10 = *(const half8*)&hterm[RB][    q][n][0];                    \
        half8 B11 = *(const half8*)&hterm[RB][4 + q][n][0];                    \
        float4v accA = {p0, p1, p2, p3};                                       \
        float4v accB = {0.f, 0.f, 0.f, 0.f};                                   \
        accA = MFMA16(A10, B10, accA);  accB = MFMA16(A20, B10, accB);         \
        accA = MFMA16(A11, B11, accA);  accB = MFMA16(A21, B11, accB);         \
        hl0 = fast_tanh(accA[0] + accB[0]); hl1 = fast_tanh(accA[1] + accB[1]);\
        hl2 = fast_tanh(accA[2] + accB[2]); hl3 = fast_tanh(accA[3] + accB[3]);\
        half2v hi01 = pk_f16(hl0, hl1), hi23 = pk_f16(hl2, hl3);               \
        uint2v whi = { __builtin_bit_cast(unsigned int, hi01),                 \
                       __builtin_bit_cast(unsigned int, hi23) };               \
        *(uint2v*)&hterm[WB][gw][n][j0] = whi;                                 \
    }

    if (grp == 0) {
        // even updates: active in phase A, xp-precompute in phase B (idle)
        XP_FROM(xa); XRELOAD(xa);                // xp for update 0
        for (int it = 0; it < SEQ_T / 2; it += 4) {
            ACTIVE_STEP(0, 1); LDS_BARRIER(); XP_FROM(xb); XRELOAD(xb); LDS_BARRIER();
            ACTIVE_STEP(0, 1); LDS_BARRIER(); XP_FROM(xc); XRELOAD(xc); LDS_BARRIER();
            ACTIVE_STEP(0, 1); LDS_BARRIER(); XP_FROM(xd); XRELOAD(xd); LDS_BARRIER();
            ACTIVE_STEP(0, 1); LDS_BARRIER(); XP_FROM(xa); XRELOAD(xa); LDS_BARRIER();
        }
    } else {
        // odd updates: xp-precompute in phase A (idle), active in phase B
        for (int it = 0; it < SEQ_T / 2; it += 4) {
            XP_FROM(xa); XRELOAD(xa); LDS_BARRIER(); ACTIVE_STEP(1, 0); LDS_BARRIER();
            XP_FROM(xb); XRELOAD(xb); LDS_BARRIER(); ACTIVE_STEP(1, 0); LDS_BARRIER();
            XP_FROM(xc); XRELOAD(xc); LDS_BARRIER(); ACTIVE_STEP(1, 0); LDS_BARRIER();
            XP_FROM(xd); XRELOAD(xd); LDS_BARRIER(); ACTIVE_STEP(1, 0); LDS_BARRIER();
        }
    }
#undef ACTIVE_STEP
#undef XRELOAD
#undef XP_FROM
#undef MFMA16

    // ---- fc epilogue: final h (update 511) lives in group 1's registers ----
    if (grp == 1) {
        float4v hv = {hl0, hl1, hl2, hl3};
        *(float4v*)&hf[n][r0] = hv;
    }
    __syncthreads();
    for (int it = tid; it < RPB * OSZ; it += 512) {
        const int b = it / OSZ;
        const int o = it - b * OSZ;
        const float* wo = fc_W + o * HID;
        float acc = fc_b[o];
        #pragma unroll
        for (int j = 0; j < HID; ++j)
            acc = fmaf(hf[b][j], wo[j], acc);
        out[(size_t)(blk0 + b) * OSZ + o] = acc;
    }
}

extern "C" void kernel_launch(void* const* d_in, const int* in_sizes, int n_in,
                              void* d_out, int out_size, void* d_ws, size_t ws_size,
                              hipStream_t stream) {
    const float* x    = (const float*)d_in[0];
    const float* W_ih = (const float*)d_in[1];
    const float* W_hh = (const float*)d_in[2];
    const float* b_ih = (const float*)d_in[3];
    const float* b_hh = (const float*)d_in[4];
    const float* fc_W = (const float*)d_in[5];
    const float* fc_b = (const float*)d_in[6];
    float* out = (float*)d_out;

    rnn_f16x2_kernel<<<BATCH / RPB, 512, 0, stream>>>(
        x, W_ih, W_hh, b_ih, b_hh, fc_W, fc_b, out);
}